// Round 7
// baseline (1144.888 us; speedup 1.0000x reference)
//
#include <hip/hip_runtime.h>
#include <hip/hip_bf16.h>
#include <math.h>

#define D 128

// ---------------- wave helpers ----------------

__device__ __forceinline__ float waveSum(float v){
    #pragma unroll
    for (int m = 1; m < 64; m <<= 1) v += __shfl_xor(v, m, 64);
    return v;
}

__device__ __forceinline__ float rdlane(float v, int lane){
    return __int_as_float(__builtin_amdgcn_readlane(__float_as_int(v), lane));
}

__device__ __forceinline__ float gelu_exact(float x){
    return 0.5f * x * (1.0f + erff(x * 0.70710678118654752f));
}

// ---------------- LDS helpers (used by pull kernels) ----------------

template<int R>
__device__ __forceinline__ void multiReduce(float* red, int j){
    __syncthreads();
    #pragma unroll
    for (int s = 64; s > 0; s >>= 1){
        if (j < s){
            #pragma unroll
            for (int r = 0; r < R; ++r) red[r*D + j] += red[r*D + j + s];
        }
        __syncthreads();
    }
}

template<int R>
__device__ __forceinline__ void matvec(const float* sh, const float* __restrict__ W,
                                       const float* __restrict__ bias, int j, float* acc){
    float bb = bias[j];
    #pragma unroll
    for (int r = 0; r < R; ++r) acc[r] = bb;
    #pragma unroll 8
    for (int i = 0; i < D; ++i){
        float w = W[i*D + j];
        #pragma unroll
        for (int r = 0; r < R; ++r) acc[r] += sh[r*D + i] * w;
    }
}

// ---------------- dense transformer block: readlane form, LDS-free ----------------
// 256-thread blocks = 4 independent waves; each wave owns RB=16 rows.
// Lane owns cols (2l, 2l+1). y[r][i] broadcast via v_readlane -> SGPR operand of
// v_fmac (no LDS, no barriers). 4 waves stream the same W rows -> L1 reuse.
#define RB 16

// acc{0,1}[r] = bias[c] + sum_i y[r][i] * W[i][c] for c = 2l, 2l+1
__device__ __forceinline__ void rl_matvec(const float* y0, const float* y1,
                                          const float* __restrict__ W,
                                          const float* __restrict__ bias,
                                          int c0, float* a0, float* a1)
{
    float2 bb = *(const float2*)&bias[c0];
    #pragma unroll
    for (int r = 0; r < RB; ++r){ a0[r] = bb.x; a1[r] = bb.y; }
    #pragma unroll 4
    for (int i = 0; i < D; i += 2){
        float2 wA = *(const float2*)&W[(size_t)i*D + c0];        // row i
        float2 wB = *(const float2*)&W[(size_t)(i+1)*D + c0];    // row i+1
        int half = i >> 1;
        #pragma unroll
        for (int r = 0; r < RB; ++r){
            float sA = rdlane(y0[r], half);   // y[r][i]   (col i stored: lane i/2, reg i&1)
            a0[r] += sA * wA.x; a1[r] += sA * wA.y;
        }
        #pragma unroll
        for (int r = 0; r < RB; ++r){
            float sB = rdlane(y1[r], half);   // y[r][i+1]
            a0[r] += sB * wB.x; a1[r] += sB * wB.y;
        }
    }
}

__global__ __launch_bounds__(256)
void k_dense(const float* __restrict__ ent,
             const float* __restrict__ g1, const float* __restrict__ be1,
             const float* __restrict__ wv, const float* __restrict__ bv,
             const float* __restrict__ wo, const float* __restrict__ bo,
             const float* __restrict__ g2, const float* __restrict__ be2,
             const float* __restrict__ w1, const float* __restrict__ b1,
             const float* __restrict__ w2, const float* __restrict__ b2,
             float* __restrict__ gcn_in, int n)
{
    const int l    = threadIdx.x & 63;        // lane within wave
    const int wave = threadIdx.x >> 6;        // 0..3
    const int c0   = 2*l;                     // this lane's two columns
    const int row0 = blockIdx.x * (4*RB) + wave * RB;   // 64 rows/block, 16/wave

    float2 g1v = *(const float2*)&g1[c0],  b1v = *(const float2*)&be1[c0];
    float2 g2v = *(const float2*)&g2[c0],  b2v = *(const float2*)&be2[c0];

    // load entity rows (coalesced float2)
    float e0[RB], e1[RB];
    #pragma unroll
    for (int r = 0; r < RB; ++r){
        int rr = row0 + r;
        if (rr < n){ float2 t = *(const float2*)&ent[(size_t)rr*D + c0]; e0[r]=t.x; e1[r]=t.y; }
        else       { e0[r]=0.0f; e1[r]=0.0f; }
    }

    // ---- LN1 (wave-shuffle reductions) ----
    float y0[RB], y1[RB];
    #pragma unroll
    for (int r = 0; r < RB; ++r){
        float mu = waveSum(e0[r] + e1[r]) * (1.0f/D);
        float d0 = e0[r]-mu, d1 = e1[r]-mu;
        float var = waveSum(d0*d0 + d1*d1) * (1.0f/D);
        float rs = rsqrtf(var + 1e-5f);
        y0[r] = d0*rs*g1v.x + b1v.x;
        y1[r] = d1*rs*g1v.y + b1v.y;
    }

    // ---- v = y@wv + bv ; ctx == v (softmax over length-1 seq == 1) ----
    float v0[RB], v1[RB];
    rl_matvec(y0, y1, wv, bv, c0, v0, v1);

    // ---- x = e + v@wo + bo ----
    float x0[RB], x1[RB];
    rl_matvec(v0, v1, wo, bo, c0, x0, x1);
    #pragma unroll
    for (int r = 0; r < RB; ++r){ x0[r] += e0[r]; x1[r] += e1[r]; }

    // ---- LN2 (reuse y regs) ----
    #pragma unroll
    for (int r = 0; r < RB; ++r){
        float mu = waveSum(x0[r] + x1[r]) * (1.0f/D);
        float d0 = x0[r]-mu, d1 = x1[r]-mu;
        float var = waveSum(d0*d0 + d1*d1) * (1.0f/D);
        float rs = rsqrtf(var + 1e-5f);
        y0[r] = d0*rs*g2v.x + b2v.x;
        y1[r] = d1*rs*g2v.y + b2v.y;
    }

    // ---- h = gelu(y2@w1 + b1) (reuse v regs) ----
    rl_matvec(y0, y1, w1, b1, c0, v0, v1);
    #pragma unroll
    for (int r = 0; r < RB; ++r){ v0[r] = gelu_exact(v0[r]); v1[r] = gelu_exact(v1[r]); }

    // ---- gcn_in = x + h@w2 + b2 (reuse y regs as acc) ----
    rl_matvec(v0, v1, w2, b2, c0, y0, y1);
    #pragma unroll
    for (int r = 0; r < RB; ++r){
        int rr = row0 + r;
        if (rr < n){
            float2 o; o.x = x0[r] + y0[r]; o.y = x1[r] + y1[r];
            *(float2*)&gcn_in[(size_t)rr*D + c0] = o;
        }
    }
}

// ---------------- device CSR build (unchanged) ----------------

__global__ __launch_bounds__(256)
void k_hist(const int* __restrict__ rows, int* __restrict__ deg, int E){
    int i = blockIdx.x * 256 + threadIdx.x;
    if (i < E) atomicAdd(&deg[rows[i]], 1);
}

__global__ __launch_bounds__(256)
void k_scan_partial(const int* __restrict__ deg, int* __restrict__ bsum, int n){
    __shared__ int s[256];
    int i = blockIdx.x * 256 + threadIdx.x;
    s[threadIdx.x] = (i < n) ? deg[i] : 0;
    __syncthreads();
    #pragma unroll
    for (int st = 128; st > 0; st >>= 1){
        if (threadIdx.x < st) s[threadIdx.x] += s[threadIdx.x + st];
        __syncthreads();
    }
    if (threadIdx.x == 0) bsum[blockIdx.x] = s[0];
}

__global__ __launch_bounds__(1024)
void k_scan_bsums(int* __restrict__ bsum, int nb){
    __shared__ int a[1024], b[1024];
    int t = threadIdx.x;
    int orig = (t < nb) ? bsum[t] : 0;
    int *src = a, *dst = b;
    src[t] = orig;
    __syncthreads();
    for (int off = 1; off < 1024; off <<= 1){
        dst[t] = src[t] + ((t >= off) ? src[t-off] : 0);
        __syncthreads();
        int* tmp = src; src = dst; dst = tmp;
    }
    if (t < nb) bsum[t] = src[t] - orig;   // exclusive
}

__global__ __launch_bounds__(256)
void k_scan_final(const int* __restrict__ deg, const int* __restrict__ bsum,
                  int* __restrict__ start, int* __restrict__ cur, int n, int total){
    __shared__ int a[256], b[256];
    int t = threadIdx.x;
    int i = blockIdx.x * 256 + t;
    int orig = (i < n) ? deg[i] : 0;
    int *src = a, *dst = b;
    src[t] = orig;
    __syncthreads();
    for (int off = 1; off < 256; off <<= 1){
        dst[t] = src[t] + ((t >= off) ? src[t-off] : 0);
        __syncthreads();
        int* tmp = src; src = dst; dst = tmp;
    }
    int excl = src[t] - orig + bsum[blockIdx.x];
    if (i < n){ start[i] = excl; cur[i] = excl; }
    if (i == n-1) start[n] = total;
}

__global__ __launch_bounds__(256)
void k_fill_gcn(const int* __restrict__ eidx, const float* __restrict__ ew,
                int* __restrict__ cur, int* __restrict__ colp, float* __restrict__ wp, int E){
    int i = blockIdx.x * 256 + threadIdx.x;
    if (i < E){
        int r = eidx[i];
        int pos = atomicAdd(&cur[r], 1);
        colp[pos] = eidx[E + i];
        wp[pos]   = ew[i];
    }
}

__global__ __launch_bounds__(256)
void k_fill_gat(const int* __restrict__ beidx, int* __restrict__ cur,
                int* __restrict__ colp, int E2){
    int i = blockIdx.x * 256 + threadIdx.x;
    if (i < E2){
        int r = beidx[i];
        int pos = atomicAdd(&cur[r], 1);
        colp[pos] = beidx[E2 + i];
    }
}

// ---------------- GCN pull + normalize + gat_w matvec + attention scalars ----------------
template<int R>
__global__ __launch_bounds__(128)
void k_gcn_pull_fin(const float* __restrict__ gcn_in,
                    const int* __restrict__ start, const int* __restrict__ colp,
                    const float* __restrict__ wp,
                    const float* __restrict__ lmbda,
                    const float* __restrict__ gat_w, const float* __restrict__ gat_b,
                    const float* __restrict__ watt,
                    float* __restrict__ gat_in,
                    float* __restrict__ dl, float* __restrict__ dr, int n)
{
    const int j = threadIdx.x;
    const int row0 = blockIdx.x * R;
    __shared__ float sh[R*D];
    __shared__ float red[R*D];
    float l1 = lmbda[0], l2 = lmbda[1];

    #pragma unroll
    for (int r = 0; r < R; ++r){
        int rr = row0 + r;
        if (rr < n){
            float acc = 0.0f, wsum = 0.0f;
            int s0 = start[rr], s1 = start[rr+1];
            for (int e = s0; e < s1; ++e){
                int   c = colp[e];
                float w = wp[e];
                acc  += w * gcn_in[(size_t)c * D + j];
                wsum += w;
            }
            float base = gcn_in[(size_t)rr * D + j];
            sh[r*D + j] = (base + l2 * acc) / (1.0f + l2 * wsum) * l1;
        } else {
            sh[r*D + j] = 0.0f;
        }
    }
    __syncthreads();

    float gv[R]; matvec<R>(sh, gat_w, gat_b, j, gv);
    #pragma unroll
    for (int r = 0; r < R; ++r){
        int rr = row0 + r;
        if (rr < n) gat_in[(size_t)rr * D + j] = gv[r];
    }

    float wl = watt[j], wr = watt[D + j];
    __syncthreads();
    #pragma unroll
    for (int r = 0; r < R; ++r) red[r*D + j] = gv[r] * wl;
    multiReduce<R>(red, j);
    if (j == 0){
        #pragma unroll
        for (int r = 0; r < R; ++r){ int rr = row0 + r; if (rr < n) dl[rr] = red[r*D]; }
    }
    __syncthreads();
    #pragma unroll
    for (int r = 0; r < R; ++r) red[r*D + j] = gv[r] * wr;
    multiReduce<R>(red, j);
    if (j == 0){
        #pragma unroll
        for (int r = 0; r < R; ++r){ int rr = row0 + r; if (rr < n) dr[rr] = red[r*D]; }
    }
}

// ---------------- GAT pull + normalize + PReLU -> out ----------------
template<int R>
__global__ __launch_bounds__(128)
void k_gat_out(const float* __restrict__ gat_in,
               const int* __restrict__ start2, const int* __restrict__ colp2,
               const int* __restrict__ bids,
               const float* __restrict__ dl, const float* __restrict__ dr,
               const float* __restrict__ prelu_a,
               float* __restrict__ out, int n)
{
    const int j = threadIdx.x;
    const int row0 = blockIdx.x * R;
    float pa = prelu_a[0];

    #pragma unroll
    for (int r = 0; r < R; ++r){
        int rr = row0 + r;
        if (rr < n){
            float dlv = dl[bids[rr]];
            int s0 = start2[rr], s1 = start2[rr+1];
            float acc = 0.0f, es = 0.0f;
            for (int e = s0; e < s1; ++e){
                int c = colp2[e];
                float ev = dlv + dr[c];
                float lr = ev > 0.0f ? ev : 0.2f * ev;
                float att = __expf(-lr);
                es  += att;
                acc += att * gat_in[(size_t)c * D + j];
            }
            float v = acc / es;   // every GAT row has its self-loop -> es > 0
            out[(size_t)rr * D + j] = v > 0.0f ? v : pa * v;
        }
    }
}

// ---------------- launch ----------------

extern "C" void kernel_launch(void* const* d_in, const int* in_sizes, int n_in,
                              void* d_out, int out_size, void* d_ws, size_t ws_size,
                              hipStream_t stream)
{
    const float* ent   = (const float*)d_in[0];
    const float* ew    = (const float*)d_in[1];
    const float* ln1_g = (const float*)d_in[2];
    const float* ln1_b = (const float*)d_in[3];
    // d_in[4..7] = wq,bq,wk,bk : dead (softmax over size-1 axis == 1 -> ctx == v)
    const float* wv    = (const float*)d_in[8];
    const float* bv    = (const float*)d_in[9];
    const float* wo    = (const float*)d_in[10];
    const float* bo    = (const float*)d_in[11];
    const float* ln2_g = (const float*)d_in[12];
    const float* ln2_b = (const float*)d_in[13];
    const float* w1    = (const float*)d_in[14];
    const float* b1    = (const float*)d_in[15];
    const float* w2    = (const float*)d_in[16];
    const float* b2    = (const float*)d_in[17];
    const float* lmbda = (const float*)d_in[18];
    const float* gat_w = (const float*)d_in[19];
    const float* gat_b = (const float*)d_in[20];
    const float* watt  = (const float*)d_in[21];
    const float* prelu = (const float*)d_in[22];
    const int* eidx    = (const int*)d_in[23];
    const int* bids    = (const int*)d_in[24];
    const int* beidx   = (const int*)d_in[25];

    const int n  = in_sizes[24];        // N entities
    const int E  = in_sizes[1];         // KG edges
    const int E2 = in_sizes[25] / 2;    // batch edges (E + N self loops)

    char* ws = (char*)d_ws;
    const size_t szND = (size_t)n * D * sizeof(float);
    size_t off = 0;
    float* bufA   = (float*)(ws + off); off += szND;                    // gcn_in
    float* bufB   = (float*)(ws + off); off += szND;                    // gat_in
    float* dl     = (float*)(ws + off); off += (size_t)n * 4;
    float* dr     = (float*)(ws + off); off += (size_t)n * 4;
    int*   deg1   = (int*)(ws + off);   off += (size_t)n * 4;           // deg1+deg2 adjacent
    int*   deg2   = (int*)(ws + off);   off += (size_t)n * 4;           //  -> single memset
    int*   start1 = (int*)(ws + off);   off += (size_t)(n+1) * 4;
    int*   start2 = (int*)(ws + off);   off += (size_t)(n+1) * 4;
    int*   cur1   = (int*)(ws + off);   off += (size_t)n * 4;
    int*   cur2   = (int*)(ws + off);   off += (size_t)n * 4;
    int*   bsum   = (int*)(ws + off);   off += 1024 * 4;
    int*   colp1  = (int*)(ws + off);   off += (size_t)E * 4;
    float* wp1    = (float*)(ws + off); off += (size_t)E * 4;
    int*   colp2  = (int*)(ws + off);   off += (size_t)E2 * 4;

    constexpr int R = 4;
    const int nblk  = (n + R - 1) / R;
    const int nscan = (n + 255) / 256;

    // dense block: readlane form, 4 waves/block x 16 rows/wave = 64 rows/block
    k_dense<<<(n + 4*RB - 1)/(4*RB), 256, 0, stream>>>(ent, ln1_g, ln1_b, wv, bv, wo, bo,
                                                       ln2_g, ln2_b, w1, b1, w2, b2, bufA, n);

    // CSR build (both edge sets)
    hipMemsetAsync(deg1, 0, (size_t)2 * n * 4, stream);
    k_hist<<<(E + 255)/256, 256, 0, stream>>>(eidx, deg1, E);
    k_hist<<<(E2 + 255)/256, 256, 0, stream>>>(beidx, deg2, E2);

    k_scan_partial<<<nscan, 256, 0, stream>>>(deg1, bsum, n);
    k_scan_bsums<<<1, 1024, 0, stream>>>(bsum, nscan);
    k_scan_final<<<nscan, 256, 0, stream>>>(deg1, bsum, start1, cur1, n, E);
    k_fill_gcn<<<(E + 255)/256, 256, 0, stream>>>(eidx, ew, cur1, colp1, wp1, E);

    k_scan_partial<<<nscan, 256, 0, stream>>>(deg2, bsum, n);
    k_scan_bsums<<<1, 1024, 0, stream>>>(bsum, nscan);
    k_scan_final<<<nscan, 256, 0, stream>>>(deg2, bsum, start2, cur2, n, E2);
    k_fill_gat<<<(E2 + 255)/256, 256, 0, stream>>>(beidx, cur2, colp2, E2);

    // GCN pull (+ gat_w matvec + attention scalars), no atomics
    k_gcn_pull_fin<R><<<nblk, 128, 0, stream>>>(bufA, start1, colp1, wp1, lmbda,
                                                gat_w, gat_b, watt, bufB, dl, dr, n);

    // GAT pull + PReLU -> out, no atomics
    k_gat_out<R><<<nblk, 128, 0, stream>>>(bufB, start2, colp2, bids, dl, dr,
                                           prelu, (float*)d_out, n);
}

// Round 8
// 845.627 us; speedup vs baseline: 1.3539x; 1.3539x over previous
//
#include <hip/hip_runtime.h>
#include <hip/hip_bf16.h>
#include <math.h>

#define D 128

typedef __attribute__((ext_vector_type(8))) short bf16x8_t;   // 8 bf16 in 4 VGPRs
typedef __attribute__((ext_vector_type(4))) float f32x4_t;    // MFMA accumulator

// f32 -> bf16 (RNE), bit-level (no NaN handling needed for this data)
__device__ __forceinline__ unsigned short f2bf(float f){
    unsigned int x = __float_as_uint(f);
    unsigned int r = x + 0x7FFFu + ((x >> 16) & 1u);
    return (unsigned short)(r >> 16);
}

__device__ __forceinline__ float gelu_exact(float x){
    return 0.5f * x * (1.0f + erff(x * 0.70710678118654752f));
}

// ---------------- LDS helpers (used by pull kernels) ----------------

template<int R>
__device__ __forceinline__ void multiReduce(float* red, int j){
    __syncthreads();
    #pragma unroll
    for (int s = 64; s > 0; s >>= 1){
        if (j < s){
            #pragma unroll
            for (int r = 0; r < R; ++r) red[r*D + j] += red[r*D + j + s];
        }
        __syncthreads();
    }
}

template<int R>
__device__ __forceinline__ void matvec(const float* sh, const float* __restrict__ W,
                                       const float* __restrict__ bias, int j, float* acc){
    float bb = bias[j];
    #pragma unroll
    for (int r = 0; r < R; ++r) acc[r] = bb;
    #pragma unroll 8
    for (int i = 0; i < D; ++i){
        float w = W[i*D + j];
        #pragma unroll
        for (int r = 0; r < R; ++r) acc[r] += sh[r*D + i] * w;
    }
}

// ---------------- weight convert + pack into B-fragment order ----------------
// Wp[m][o], o = (s<<11)|(k0<<9)|(lane<<3)|j  holds  W_m[k][n], k=32*k0+8*(lane>>4)+j,
// n=16*s+(lane&15).  A wave's B-frag load (s,k0) is then 64 lanes x 16B contiguous.
__global__ __launch_bounds__(256)
void k_cvt(const float* __restrict__ w0, const float* __restrict__ w1,
           const float* __restrict__ w2, const float* __restrict__ w3,
           unsigned short* __restrict__ out)
{
    int m = blockIdx.y;
    const float* W = (m == 0) ? w0 : (m == 1) ? w1 : (m == 2) ? w2 : w3;
    int o = blockIdx.x * 256 + threadIdx.x;           // 0..16383
    int j  = o & 7;
    int l  = (o >> 3) & 63;
    int k0 = (o >> 9) & 3;
    int s  = o >> 11;
    int k  = 32*k0 + 8*(l >> 4) + j;
    int nn = 16*s + (l & 15);
    out[(size_t)m * 16384 + o] = f2bf(W[k*D + nn]);
}

// ---------------- dense transformer block: MFMA form ----------------
// 256 thr = 4 waves; 64 rows/block, wave owns 16x128 tile.
// C-layout per thread: rows 4g+r (g=lane>>4, r=0..3), cols 16s+c (c=lane&15, s=0..7).
// Per stage: pointwise (f32) -> f2bf -> per-wave LDS X[16][136] -> A-frags (ds_read_b128)
// -> 32 mfma_f32_16x16x32_bf16 with packed global B-frags.

__device__ __forceinline__ void mm_stage(const unsigned short* __restrict__ Wp,
                                         const float* __restrict__ bias,
                                         const unsigned short (*Xw)[136],
                                         int c, int g, int l, f32x4_t acc[8])
{
    #pragma unroll
    for (int s = 0; s < 8; ++s){
        float bb = bias[16*s + c];
        acc[s] = (f32x4_t){bb, bb, bb, bb};
    }
    #pragma unroll
    for (int k0 = 0; k0 < 4; ++k0){
        bf16x8_t a = *(const bf16x8_t*)&Xw[c][32*k0 + 8*g];
        #pragma unroll
        for (int s = 0; s < 8; ++s){
            bf16x8_t b = *(const bf16x8_t*)&Wp[(size_t)(((s*4 + k0)*64 + l) * 8)];
            acc[s] = __builtin_amdgcn_mfma_f32_16x16x32_bf16(a, b, acc[s], 0, 0, 0);
        }
    }
}

__global__ __launch_bounds__(256)
void k_dense(const float* __restrict__ ent,
             const float* __restrict__ g1, const float* __restrict__ be1,
             const float* __restrict__ g2, const float* __restrict__ be2,
             const float* __restrict__ bv, const float* __restrict__ bo,
             const float* __restrict__ b1, const float* __restrict__ b2,
             const unsigned short* __restrict__ Wp,   // packed bf16 wv,wo,w1,w2
             float* __restrict__ gcn_in, int n)
{
    __shared__ unsigned short X[4][16][136];          // per-wave bf16 activation tile
    const int tid = threadIdx.x;
    const int wv_ = tid >> 6, l = tid & 63, c = l & 15, g = l >> 4;
    const int row0 = blockIdx.x * 64 + wv_ * 16;
    unsigned short (*Xw)[136] = X[wv_];

    // ---- load e in C-layout (f32, kept for residuals) ----
    float ev[8][4];
    #pragma unroll
    for (int s = 0; s < 8; ++s)
        #pragma unroll
        for (int r = 0; r < 4; ++r){
            int rr = row0 + 4*g + r; if (rr >= n) rr = n - 1;
            ev[s][r] = ent[(size_t)rr * D + 16*s + c];
        }

    // ---- LN1 -> bf16 X ----
    {
        float gg[8], bb[8];
        #pragma unroll
        for (int s = 0; s < 8; ++s){ gg[s] = g1[16*s + c]; bb[s] = be1[16*s + c]; }
        #pragma unroll
        for (int r = 0; r < 4; ++r){
            float t = 0.0f;
            #pragma unroll
            for (int s = 0; s < 8; ++s) t += ev[s][r];
            t += __shfl_xor(t,1); t += __shfl_xor(t,2); t += __shfl_xor(t,4); t += __shfl_xor(t,8);
            float mu = t * (1.0f/128.0f);
            float q = 0.0f;
            #pragma unroll
            for (int s = 0; s < 8; ++s){ float d = ev[s][r]-mu; q += d*d; }
            q += __shfl_xor(q,1); q += __shfl_xor(q,2); q += __shfl_xor(q,4); q += __shfl_xor(q,8);
            float rs = rsqrtf(q*(1.0f/128.0f) + 1e-5f);
            #pragma unroll
            for (int s = 0; s < 8; ++s)
                Xw[4*g + r][16*s + c] = f2bf((ev[s][r]-mu)*rs*gg[s] + bb[s]);
        }
    }

    f32x4_t acc[8];

    // ---- v = y@wv + bv ; ctx == v (softmax over length-1 seq == 1) ----
    mm_stage(Wp + 0*16384, bv, Xw, c, g, l, acc);
    #pragma unroll
    for (int s = 0; s < 8; ++s)
        #pragma unroll
        for (int r = 0; r < 4; ++r)
            Xw[4*g + r][16*s + c] = f2bf(acc[s][r]);

    // ---- x = e + v@wo + bo  (into ev) ----
    mm_stage(Wp + 1*16384, bo, Xw, c, g, l, acc);
    #pragma unroll
    for (int s = 0; s < 8; ++s)
        #pragma unroll
        for (int r = 0; r < 4; ++r)
            ev[s][r] += acc[s][r];

    // ---- LN2 -> bf16 X ----
    {
        float gg[8], bb[8];
        #pragma unroll
        for (int s = 0; s < 8; ++s){ gg[s] = g2[16*s + c]; bb[s] = be2[16*s + c]; }
        #pragma unroll
        for (int r = 0; r < 4; ++r){
            float t = 0.0f;
            #pragma unroll
            for (int s = 0; s < 8; ++s) t += ev[s][r];
            t += __shfl_xor(t,1); t += __shfl_xor(t,2); t += __shfl_xor(t,4); t += __shfl_xor(t,8);
            float mu = t * (1.0f/128.0f);
            float q = 0.0f;
            #pragma unroll
            for (int s = 0; s < 8; ++s){ float d = ev[s][r]-mu; q += d*d; }
            q += __shfl_xor(q,1); q += __shfl_xor(q,2); q += __shfl_xor(q,4); q += __shfl_xor(q,8);
            float rs = rsqrtf(q*(1.0f/128.0f) + 1e-5f);
            #pragma unroll
            for (int s = 0; s < 8; ++s)
                Xw[4*g + r][16*s + c] = f2bf((ev[s][r]-mu)*rs*gg[s] + bb[s]);
        }
    }

    // ---- h = gelu(y2@w1 + b1) ----
    mm_stage(Wp + 2*16384, b1, Xw, c, g, l, acc);
    #pragma unroll
    for (int s = 0; s < 8; ++s)
        #pragma unroll
        for (int r = 0; r < 4; ++r)
            Xw[4*g + r][16*s + c] = f2bf(gelu_exact(acc[s][r]));

    // ---- gcn_in = x + h@w2 + b2 ----
    mm_stage(Wp + 3*16384, b2, Xw, c, g, l, acc);
    #pragma unroll
    for (int s = 0; s < 8; ++s)
        #pragma unroll
        for (int r = 0; r < 4; ++r){
            int rr = row0 + 4*g + r;
            if (rr < n) gcn_in[(size_t)rr * D + 16*s + c] = ev[s][r] + acc[s][r];
        }
}

// ---------------- device CSR build (unchanged) ----------------

__global__ __launch_bounds__(256)
void k_hist(const int* __restrict__ rows, int* __restrict__ deg, int E){
    int i = blockIdx.x * 256 + threadIdx.x;
    if (i < E) atomicAdd(&deg[rows[i]], 1);
}

__global__ __launch_bounds__(256)
void k_scan_partial(const int* __restrict__ deg, int* __restrict__ bsum, int n){
    __shared__ int s[256];
    int i = blockIdx.x * 256 + threadIdx.x;
    s[threadIdx.x] = (i < n) ? deg[i] : 0;
    __syncthreads();
    #pragma unroll
    for (int st = 128; st > 0; st >>= 1){
        if (threadIdx.x < st) s[threadIdx.x] += s[threadIdx.x + st];
        __syncthreads();
    }
    if (threadIdx.x == 0) bsum[blockIdx.x] = s[0];
}

__global__ __launch_bounds__(1024)
void k_scan_bsums(int* __restrict__ bsum, int nb){
    __shared__ int a[1024], b[1024];
    int t = threadIdx.x;
    int orig = (t < nb) ? bsum[t] : 0;
    int *src = a, *dst = b;
    src[t] = orig;
    __syncthreads();
    for (int off = 1; off < 1024; off <<= 1){
        dst[t] = src[t] + ((t >= off) ? src[t-off] : 0);
        __syncthreads();
        int* tmp = src; src = dst; dst = tmp;
    }
    if (t < nb) bsum[t] = src[t] - orig;   // exclusive
}

__global__ __launch_bounds__(256)
void k_scan_final(const int* __restrict__ deg, const int* __restrict__ bsum,
                  int* __restrict__ start, int* __restrict__ cur, int n, int total){
    __shared__ int a[256], b[256];
    int t = threadIdx.x;
    int i = blockIdx.x * 256 + t;
    int orig = (i < n) ? deg[i] : 0;
    int *src = a, *dst = b;
    src[t] = orig;
    __syncthreads();
    for (int off = 1; off < 256; off <<= 1){
        dst[t] = src[t] + ((t >= off) ? src[t-off] : 0);
        __syncthreads();
        int* tmp = src; src = dst; dst = tmp;
    }
    int excl = src[t] - orig + bsum[blockIdx.x];
    if (i < n){ start[i] = excl; cur[i] = excl; }
    if (i == n-1) start[n] = total;
}

__global__ __launch_bounds__(256)
void k_fill_gcn(const int* __restrict__ eidx, const float* __restrict__ ew,
                int* __restrict__ cur, int* __restrict__ colp, float* __restrict__ wp, int E){
    int i = blockIdx.x * 256 + threadIdx.x;
    if (i < E){
        int r = eidx[i];
        int pos = atomicAdd(&cur[r], 1);
        colp[pos] = eidx[E + i];
        wp[pos]   = ew[i];
    }
}

__global__ __launch_bounds__(256)
void k_fill_gat(const int* __restrict__ beidx, int* __restrict__ cur,
                int* __restrict__ colp, int E2){
    int i = blockIdx.x * 256 + threadIdx.x;
    if (i < E2){
        int r = beidx[i];
        int pos = atomicAdd(&cur[r], 1);
        colp[pos] = beidx[E2 + i];
    }
}

// ---------------- GCN pull + normalize + gat_w matvec + attention scalars ----------------
template<int R>
__global__ __launch_bounds__(128)
void k_gcn_pull_fin(const float* __restrict__ gcn_in,
                    const int* __restrict__ start, const int* __restrict__ colp,
                    const float* __restrict__ wp,
                    const float* __restrict__ lmbda,
                    const float* __restrict__ gat_w, const float* __restrict__ gat_b,
                    const float* __restrict__ watt,
                    float* __restrict__ gat_in,
                    float* __restrict__ dl, float* __restrict__ dr, int n)
{
    const int j = threadIdx.x;
    const int row0 = blockIdx.x * R;
    __shared__ float sh[R*D];
    __shared__ float red[R*D];
    float l1 = lmbda[0], l2 = lmbda[1];

    #pragma unroll
    for (int r = 0; r < R; ++r){
        int rr = row0 + r;
        if (rr < n){
            float acc = 0.0f, wsum = 0.0f;
            int s0 = start[rr], s1 = start[rr+1];
            for (int e = s0; e < s1; ++e){
                int   c = colp[e];
                float w = wp[e];
                acc  += w * gcn_in[(size_t)c * D + j];
                wsum += w;
            }
            float base = gcn_in[(size_t)rr * D + j];
            sh[r*D + j] = (base + l2 * acc) / (1.0f + l2 * wsum) * l1;
        } else {
            sh[r*D + j] = 0.0f;
        }
    }
    __syncthreads();

    float gv[R]; matvec<R>(sh, gat_w, gat_b, j, gv);
    #pragma unroll
    for (int r = 0; r < R; ++r){
        int rr = row0 + r;
        if (rr < n) gat_in[(size_t)rr * D + j] = gv[r];
    }

    float wl = watt[j], wr = watt[D + j];
    __syncthreads();
    #pragma unroll
    for (int r = 0; r < R; ++r) red[r*D + j] = gv[r] * wl;
    multiReduce<R>(red, j);
    if (j == 0){
        #pragma unroll
        for (int r = 0; r < R; ++r){ int rr = row0 + r; if (rr < n) dl[rr] = red[r*D]; }
    }
    __syncthreads();
    #pragma unroll
    for (int r = 0; r < R; ++r) red[r*D + j] = gv[r] * wr;
    multiReduce<R>(red, j);
    if (j == 0){
        #pragma unroll
        for (int r = 0; r < R; ++r){ int rr = row0 + r; if (rr < n) dr[rr] = red[r*D]; }
    }
}

// ---------------- GAT pull + normalize + PReLU -> out ----------------
template<int R>
__global__ __launch_bounds__(128)
void k_gat_out(const float* __restrict__ gat_in,
               const int* __restrict__ start2, const int* __restrict__ colp2,
               const int* __restrict__ bids,
               const float* __restrict__ dl, const float* __restrict__ dr,
               const float* __restrict__ prelu_a,
               float* __restrict__ out, int n)
{
    const int j = threadIdx.x;
    const int row0 = blockIdx.x * R;
    float pa = prelu_a[0];

    #pragma unroll
    for (int r = 0; r < R; ++r){
        int rr = row0 + r;
        if (rr < n){
            float dlv = dl[bids[rr]];
            int s0 = start2[rr], s1 = start2[rr+1];
            float acc = 0.0f, es = 0.0f;
            for (int e = s0; e < s1; ++e){
                int c = colp2[e];
                float ev = dlv + dr[c];
                float lr = ev > 0.0f ? ev : 0.2f * ev;
                float att = __expf(-lr);
                es  += att;
                acc += att * gat_in[(size_t)c * D + j];
            }
            float v = acc / es;   // every GAT row has its self-loop -> es > 0
            out[(size_t)rr * D + j] = v > 0.0f ? v : pa * v;
        }
    }
}

// ---------------- launch ----------------

extern "C" void kernel_launch(void* const* d_in, const int* in_sizes, int n_in,
                              void* d_out, int out_size, void* d_ws, size_t ws_size,
                              hipStream_t stream)
{
    const float* ent   = (const float*)d_in[0];
    const float* ew    = (const float*)d_in[1];
    const float* ln1_g = (const float*)d_in[2];
    const float* ln1_b = (const float*)d_in[3];
    // d_in[4..7] = wq,bq,wk,bk : dead (softmax over size-1 axis == 1 -> ctx == v)
    const float* wv    = (const float*)d_in[8];
    const float* bv    = (const float*)d_in[9];
    const float* wo    = (const float*)d_in[10];
    const float* bo    = (const float*)d_in[11];
    const float* ln2_g = (const float*)d_in[12];
    const float* ln2_b = (const float*)d_in[13];
    const float* w1    = (const float*)d_in[14];
    const float* b1    = (const float*)d_in[15];
    const float* w2    = (const float*)d_in[16];
    const float* b2    = (const float*)d_in[17];
    const float* lmbda = (const float*)d_in[18];
    const float* gat_w = (const float*)d_in[19];
    const float* gat_b = (const float*)d_in[20];
    const float* watt  = (const float*)d_in[21];
    const float* prelu = (const float*)d_in[22];
    const int* eidx    = (const int*)d_in[23];
    const int* bids    = (const int*)d_in[24];
    const int* beidx   = (const int*)d_in[25];

    const int n  = in_sizes[24];        // N entities
    const int E  = in_sizes[1];         // KG edges
    const int E2 = in_sizes[25] / 2;    // batch edges (E + N self loops)

    char* ws = (char*)d_ws;
    const size_t szND = (size_t)n * D * sizeof(float);
    size_t off = 0;
    float* bufA   = (float*)(ws + off); off += szND;                    // gcn_in
    float* bufB   = (float*)(ws + off); off += szND;                    // gat_in
    float* dl     = (float*)(ws + off); off += (size_t)n * 4;
    float* dr     = (float*)(ws + off); off += (size_t)n * 4;
    int*   deg1   = (int*)(ws + off);   off += (size_t)n * 4;           // deg1+deg2 adjacent
    int*   deg2   = (int*)(ws + off);   off += (size_t)n * 4;           //  -> single memset
    int*   start1 = (int*)(ws + off);   off += (size_t)(n+1) * 4;
    int*   start2 = (int*)(ws + off);   off += (size_t)(n+1) * 4;
    int*   cur1   = (int*)(ws + off);   off += (size_t)n * 4;
    int*   cur2   = (int*)(ws + off);   off += (size_t)n * 4;
    int*   bsum   = (int*)(ws + off);   off += 1024 * 4;
    int*   colp1  = (int*)(ws + off);   off += (size_t)E * 4;
    float* wp1    = (float*)(ws + off); off += (size_t)E * 4;
    int*   colp2  = (int*)(ws + off);   off += (size_t)E2 * 4;
    off = (off + 15) & ~(size_t)15;
    unsigned short* Wp = (unsigned short*)(ws + off); off += (size_t)4 * 16384 * 2;

    constexpr int R = 4;
    const int nblk  = (n + R - 1) / R;
    const int nscan = (n + 255) / 256;

    // pack bf16 weights in B-frag order (wv, wo, w1, w2)
    k_cvt<<<dim3(64, 4), 256, 0, stream>>>(wv, wo, w1, w2, Wp);

    // dense block: MFMA form, 4 waves/block x 16 rows/wave = 64 rows/block
    k_dense<<<(n + 63)/64, 256, 0, stream>>>(ent, ln1_g, ln1_b, ln2_g, ln2_b,
                                             bv, bo, b1, b2, Wp, bufA, n);

    // CSR build (both edge sets)
    hipMemsetAsync(deg1, 0, (size_t)2 * n * 4, stream);
    k_hist<<<(E + 255)/256, 256, 0, stream>>>(eidx, deg1, E);
    k_hist<<<(E2 + 255)/256, 256, 0, stream>>>(beidx, deg2, E2);

    k_scan_partial<<<nscan, 256, 0, stream>>>(deg1, bsum, n);
    k_scan_bsums<<<1, 1024, 0, stream>>>(bsum, nscan);
    k_scan_final<<<nscan, 256, 0, stream>>>(deg1, bsum, start1, cur1, n, E);
    k_fill_gcn<<<(E + 255)/256, 256, 0, stream>>>(eidx, ew, cur1, colp1, wp1, E);

    k_scan_partial<<<nscan, 256, 0, stream>>>(deg2, bsum, n);
    k_scan_bsums<<<1, 1024, 0, stream>>>(bsum, nscan);
    k_scan_final<<<nscan, 256, 0, stream>>>(deg2, bsum, start2, cur2, n, E2);
    k_fill_gat<<<(E2 + 255)/256, 256, 0, stream>>>(beidx, cur2, colp2, E2);

    // GCN pull (+ gat_w matvec + attention scalars), no atomics
    k_gcn_pull_fin<R><<<nblk, 128, 0, stream>>>(bufA, start1, colp1, wp1, lmbda,
                                                gat_w, gat_b, watt, bufB, dl, dr, n);

    // GAT pull + PReLU -> out, no atomics
    k_gat_out<R><<<nblk, 128, 0, stream>>>(bufB, start2, colp2, bids, dl, dr,
                                           prelu, (float*)d_out, n);
}

// Round 11
// 728.377 us; speedup vs baseline: 1.5718x; 1.1610x over previous
//
#include <hip/hip_runtime.h>
#include <hip/hip_bf16.h>
#include <math.h>

#define D 128

typedef __attribute__((ext_vector_type(8))) short bf16x8_t;   // 8 bf16 in 4 VGPRs
typedef __attribute__((ext_vector_type(4))) float f32x4_t;    // MFMA accumulator

// f32 -> bf16 (RNE), bit-level (no NaN handling needed for this data)
__device__ __forceinline__ unsigned short f2bf(float f){
    unsigned int x = __float_as_uint(f);
    unsigned int r = x + 0x7FFFu + ((x >> 16) & 1u);
    return (unsigned short)(r >> 16);
}

__device__ __forceinline__ float gelu_exact(float x){
    return 0.5f * x * (1.0f + erff(x * 0.70710678118654752f));
}

__device__ __forceinline__ float waveSum(float v){
    #pragma unroll
    for (int m = 1; m < 64; m <<= 1) v += __shfl_xor(v, m, 64);
    return v;
}

// ---------------- weight convert + pack into B-fragment order ----------------
// Wp[m][o], o = (s<<11)|(k0<<9)|(lane<<3)|j  holds  W_m[k][n], k=32*k0+8*(lane>>4)+j,
// n=16*s+(lane&15).  A wave's B-frag load (s,k0) is then 64 lanes x 16B contiguous.
__global__ __launch_bounds__(256)
void k_cvt(const float* __restrict__ w0, const float* __restrict__ w1,
           const float* __restrict__ w2, const float* __restrict__ w3,
           const float* __restrict__ w4,
           unsigned short* __restrict__ out)
{
    int m = blockIdx.y;
    const float* W = (m == 0) ? w0 : (m == 1) ? w1 : (m == 2) ? w2 : (m == 3) ? w3 : w4;
    int o = blockIdx.x * 256 + threadIdx.x;           // 0..16383
    int j  = o & 7;
    int l  = (o >> 3) & 63;
    int k0 = (o >> 9) & 3;
    int s  = o >> 11;
    int k  = 32*k0 + 8*(l >> 4) + j;
    int nn = 16*s + (l & 15);
    out[(size_t)m * 16384 + o] = f2bf(W[k*D + nn]);
}

// ---------------- dense transformer block: MFMA form ----------------
// 256 thr = 4 waves; 64 rows/block, wave owns 16x128 tile.
// C-layout per thread: rows 4g+r (g=lane>>4, r=0..3), cols 16s+c (c=lane&15, s=0..7).
// Outputs Z = gcn_in @ gat_w  (GCN aggregation and gat_w projection commute).

template<bool HASB>
__device__ __forceinline__ void mm_stage(const unsigned short* __restrict__ Wp,
                                         const float* __restrict__ bias,
                                         const unsigned short (*Xw)[136],
                                         int c, int g, int l, f32x4_t acc[8])
{
    #pragma unroll
    for (int s = 0; s < 8; ++s){
        float bb = HASB ? bias[16*s + c] : 0.0f;
        acc[s] = (f32x4_t){bb, bb, bb, bb};
    }
    #pragma unroll
    for (int k0 = 0; k0 < 4; ++k0){
        bf16x8_t a = *(const bf16x8_t*)&Xw[c][32*k0 + 8*g];
        #pragma unroll
        for (int s = 0; s < 8; ++s){
            bf16x8_t b = *(const bf16x8_t*)&Wp[(size_t)(((s*4 + k0)*64 + l) * 8)];
            acc[s] = __builtin_amdgcn_mfma_f32_16x16x32_bf16(a, b, acc[s], 0, 0, 0);
        }
    }
}

__global__ __launch_bounds__(256)
void k_dense(const float* __restrict__ ent,
             const float* __restrict__ g1, const float* __restrict__ be1,
             const float* __restrict__ g2, const float* __restrict__ be2,
             const float* __restrict__ bv, const float* __restrict__ bo,
             const float* __restrict__ b1, const float* __restrict__ b2,
             const unsigned short* __restrict__ Wp,   // packed bf16 wv,wo,w1,w2,gat_w
             float* __restrict__ Zout, int n)
{
    __shared__ unsigned short X[4][16][136];          // per-wave bf16 activation tile
    const int tid = threadIdx.x;
    const int wv_ = tid >> 6, l = tid & 63, c = l & 15, g = l >> 4;
    const int row0 = blockIdx.x * 64 + wv_ * 16;
    unsigned short (*Xw)[136] = X[wv_];

    // ---- load e in C-layout (f32, kept for residuals) ----
    float ev[8][4];
    #pragma unroll
    for (int s = 0; s < 8; ++s)
        #pragma unroll
        for (int r = 0; r < 4; ++r){
            int rr = row0 + 4*g + r; if (rr >= n) rr = n - 1;
            ev[s][r] = ent[(size_t)rr * D + 16*s + c];
        }

    // ---- LN1 -> bf16 X ----
    {
        float gg[8], bb[8];
        #pragma unroll
        for (int s = 0; s < 8; ++s){ gg[s] = g1[16*s + c]; bb[s] = be1[16*s + c]; }
        #pragma unroll
        for (int r = 0; r < 4; ++r){
            float t = 0.0f;
            #pragma unroll
            for (int s = 0; s < 8; ++s) t += ev[s][r];
            t += __shfl_xor(t,1); t += __shfl_xor(t,2); t += __shfl_xor(t,4); t += __shfl_xor(t,8);
            float mu = t * (1.0f/128.0f);
            float q = 0.0f;
            #pragma unroll
            for (int s = 0; s < 8; ++s){ float d = ev[s][r]-mu; q += d*d; }
            q += __shfl_xor(q,1); q += __shfl_xor(q,2); q += __shfl_xor(q,4); q += __shfl_xor(q,8);
            float rs = rsqrtf(q*(1.0f/128.0f) + 1e-5f);
            #pragma unroll
            for (int s = 0; s < 8; ++s)
                Xw[4*g + r][16*s + c] = f2bf((ev[s][r]-mu)*rs*gg[s] + bb[s]);
        }
    }

    f32x4_t acc[8];

    // ---- v = y@wv + bv ; ctx == v (softmax over length-1 seq == 1) ----
    mm_stage<true>(Wp + 0*16384, bv, Xw, c, g, l, acc);
    #pragma unroll
    for (int s = 0; s < 8; ++s)
        #pragma unroll
        for (int r = 0; r < 4; ++r)
            Xw[4*g + r][16*s + c] = f2bf(acc[s][r]);

    // ---- x = e + v@wo + bo  (into ev) ----
    mm_stage<true>(Wp + 1*16384, bo, Xw, c, g, l, acc);
    #pragma unroll
    for (int s = 0; s < 8; ++s)
        #pragma unroll
        for (int r = 0; r < 4; ++r)
            ev[s][r] += acc[s][r];

    // ---- LN2 -> bf16 X ----
    {
        float gg[8], bb[8];
        #pragma unroll
        for (int s = 0; s < 8; ++s){ gg[s] = g2[16*s + c]; bb[s] = be2[16*s + c]; }
        #pragma unroll
        for (int r = 0; r < 4; ++r){
            float t = 0.0f;
            #pragma unroll
            for (int s = 0; s < 8; ++s) t += ev[s][r];
            t += __shfl_xor(t,1); t += __shfl_xor(t,2); t += __shfl_xor(t,4); t += __shfl_xor(t,8);
            float mu = t * (1.0f/128.0f);
            float q = 0.0f;
            #pragma unroll
            for (int s = 0; s < 8; ++s){ float d = ev[s][r]-mu; q += d*d; }
            q += __shfl_xor(q,1); q += __shfl_xor(q,2); q += __shfl_xor(q,4); q += __shfl_xor(q,8);
            float rs = rsqrtf(q*(1.0f/128.0f) + 1e-5f);
            #pragma unroll
            for (int s = 0; s < 8; ++s)
                Xw[4*g + r][16*s + c] = f2bf((ev[s][r]-mu)*rs*gg[s] + bb[s]);
        }
    }

    // ---- h = gelu(y2@w1 + b1) ----
    mm_stage<true>(Wp + 2*16384, b1, Xw, c, g, l, acc);
    #pragma unroll
    for (int s = 0; s < 8; ++s)
        #pragma unroll
        for (int r = 0; r < 4; ++r)
            Xw[4*g + r][16*s + c] = f2bf(gelu_exact(acc[s][r]));

    // ---- gcn = x + h@w2 + b2 -> bf16 X ----
    mm_stage<true>(Wp + 3*16384, b2, Xw, c, g, l, acc);
    #pragma unroll
    for (int s = 0; s < 8; ++s)
        #pragma unroll
        for (int r = 0; r < 4; ++r)
            Xw[4*g + r][16*s + c] = f2bf(ev[s][r] + acc[s][r]);

    // ---- Z = gcn @ gat_w  (no bias; gat_b applied after GCN scaling) ----
    mm_stage<false>(Wp + 4*16384, nullptr, Xw, c, g, l, acc);
    #pragma unroll
    for (int s = 0; s < 8; ++s)
        #pragma unroll
        for (int r = 0; r < 4; ++r){
            int rr = row0 + 4*g + r;
            if (rr < n) Zout[(size_t)rr * D + 16*s + c] = acc[s][r];
        }
}

// ---------------- device CSR build (unchanged) ----------------

__global__ __launch_bounds__(256)
void k_hist(const int* __restrict__ rows, int* __restrict__ deg, int E){
    int i = blockIdx.x * 256 + threadIdx.x;
    if (i < E) atomicAdd(&deg[rows[i]], 1);
}

__global__ __launch_bounds__(256)
void k_scan_partial(const int* __restrict__ deg, int* __restrict__ bsum, int n){
    __shared__ int s[256];
    int i = blockIdx.x * 256 + threadIdx.x;
    s[threadIdx.x] = (i < n) ? deg[i] : 0;
    __syncthreads();
    #pragma unroll
    for (int st = 128; st > 0; st >>= 1){
        if (threadIdx.x < st) s[threadIdx.x] += s[threadIdx.x + st];
        __syncthreads();
    }
    if (threadIdx.x == 0) bsum[blockIdx.x] = s[0];
}

__global__ __launch_bounds__(1024)
void k_scan_bsums(int* __restrict__ bsum, int nb){
    __shared__ int a[1024], b[1024];
    int t = threadIdx.x;
    int orig = (t < nb) ? bsum[t] : 0;
    int *src = a, *dst = b;
    src[t] = orig;
    __syncthreads();
    for (int off = 1; off < 1024; off <<= 1){
        dst[t] = src[t] + ((t >= off) ? src[t-off] : 0);
        __syncthreads();
        int* tmp = src; src = dst; dst = tmp;
    }
    if (t < nb) bsum[t] = src[t] - orig;   // exclusive
}

__global__ __launch_bounds__(256)
void k_scan_final(const int* __restrict__ deg, const int* __restrict__ bsum,
                  int* __restrict__ start, int* __restrict__ cur, int n, int total){
    __shared__ int a[256], b[256];
    int t = threadIdx.x;
    int i = blockIdx.x * 256 + t;
    int orig = (i < n) ? deg[i] : 0;
    int *src = a, *dst = b;
    src[t] = orig;
    __syncthreads();
    for (int off = 1; off < 256; off <<= 1){
        dst[t] = src[t] + ((t >= off) ? src[t-off] : 0);
        __syncthreads();
        int* tmp = src; src = dst; dst = tmp;
    }
    int excl = src[t] - orig + bsum[blockIdx.x];
    if (i < n){ start[i] = excl; cur[i] = excl; }
    if (i == n-1) start[n] = total;
}

__global__ __launch_bounds__(256)
void k_fill_gcn(const int* __restrict__ eidx, const float* __restrict__ ew,
                int* __restrict__ cur, int* __restrict__ colp, float* __restrict__ wp, int E){
    int i = blockIdx.x * 256 + threadIdx.x;
    if (i < E){
        int r = eidx[i];
        int pos = atomicAdd(&cur[r], 1);
        colp[pos] = eidx[E + i];
        wp[pos]   = ew[i];
    }
}

__global__ __launch_bounds__(256)
void k_fill_gat(const int* __restrict__ beidx, int* __restrict__ cur,
                int* __restrict__ colp, int E2){
    int i = blockIdx.x * 256 + threadIdx.x;
    if (i < E2){
        int r = beidx[i];
        int pos = atomicAdd(&cur[r], 1);
        colp[pos] = beidx[E2 + i];
    }
}

// ---------------- GCN pull (wave-per-row): gat_in = (Z + l2*neigh(Z))*inv*l1 + gat_b ----
// Also dl[r] = gat_in[r]·watt[:D], dr[r] = gat_in[r]·watt[D:] via waveSum.
#define PW 4   // rows per wave
__global__ __launch_bounds__(256)
void k_gcn_pull(const float* __restrict__ Z,
                const int* __restrict__ start, const int* __restrict__ colp,
                const float* __restrict__ wp,
                const float* __restrict__ lmbda,
                const float* __restrict__ gat_b, const float* __restrict__ watt,
                float* __restrict__ gat_in,
                float* __restrict__ dl, float* __restrict__ dr, int n)
{
    const int l   = threadIdx.x & 63;
    const int wv_ = threadIdx.x >> 6;
    const int c0  = 2*l;
    const float l1 = lmbda[0], l2 = lmbda[1];
    const float2 gb = *(const float2*)&gat_b[c0];
    const float2 wl = *(const float2*)&watt[c0];
    const float2 wr = *(const float2*)&watt[D + c0];
    const int row0 = (blockIdx.x * 4 + wv_) * PW;

    #pragma unroll
    for (int r = 0; r < PW; ++r){
        int rr = row0 + r;
        if (rr < n){
            int rs = __builtin_amdgcn_readfirstlane(rr);   // force SGPR -> s_load path
            int s0 = start[rs], s1 = start[rs+1];
            float2 base = *(const float2*)&Z[(size_t)rs * D + c0];
            float accx = 0.0f, accy = 0.0f, wsum = 0.0f;
            for (int e = s0; e < s1; ++e){
                int   c = colp[e];                         // wave-uniform scalar load
                float w = wp[e];
                float2 zr = *(const float2*)&Z[(size_t)c * D + c0];
                accx += w * zr.x; accy += w * zr.y; wsum += w;
            }
            float inv = l1 / (1.0f + l2 * wsum);
            float gx = (base.x + l2*accx) * inv + gb.x;
            float gy = (base.y + l2*accy) * inv + gb.y;
            float2 o; o.x = gx; o.y = gy;
            *(float2*)&gat_in[(size_t)rs * D + c0] = o;
            float dlv = waveSum(gx*wl.x + gy*wl.y);
            float drv = waveSum(gx*wr.x + gy*wr.y);
            if (l == 0){ dl[rs] = dlv; dr[rs] = drv; }
        }
    }
}

// ---------------- GAT pull (wave-per-row) + normalize + PReLU -> out ----------------
__global__ __launch_bounds__(256)
void k_gat_out(const float* __restrict__ gat_in,
               const int* __restrict__ start2, const int* __restrict__ colp2,
               const int* __restrict__ bids,
               const float* __restrict__ dl, const float* __restrict__ dr,
               const float* __restrict__ prelu_a,
               float* __restrict__ out, int n)
{
    const int l   = threadIdx.x & 63;
    const int wv_ = threadIdx.x >> 6;
    const int c0  = 2*l;
    const float pa = prelu_a[0];
    const int row0 = (blockIdx.x * 4 + wv_) * PW;

    #pragma unroll
    for (int r = 0; r < PW; ++r){
        int rr = row0 + r;
        if (rr < n){
            int rs = __builtin_amdgcn_readfirstlane(rr);
            float dlv = dl[bids[rs]];
            int s0 = start2[rs], s1 = start2[rs+1];
            float accx = 0.0f, accy = 0.0f, es = 0.0f;
            for (int e = s0; e < s1; ++e){
                int c = colp2[e];                          // wave-uniform scalar load
                float ev = dlv + dr[c];
                float lr = ev > 0.0f ? ev : 0.2f * ev;
                float att = __expf(-lr);
                float2 g = *(const float2*)&gat_in[(size_t)c * D + c0];
                accx += att * g.x; accy += att * g.y; es += att;
            }
            float is = 1.0f / es;                          // self-loop guarantees es > 0
            float vx = accx * is, vy = accy * is;
            float2 o;
            o.x = vx > 0.0f ? vx : pa * vx;
            o.y = vy > 0.0f ? vy : pa * vy;
            *(float2*)&out[(size_t)rr * D + c0] = o;
        }
    }
}

// ---------------- launch ----------------

extern "C" void kernel_launch(void* const* d_in, const int* in_sizes, int n_in,
                              void* d_out, int out_size, void* d_ws, size_t ws_size,
                              hipStream_t stream)
{
    const float* ent   = (const float*)d_in[0];
    const float* ew    = (const float*)d_in[1];
    const float* ln1_g = (const float*)d_in[2];
    const float* ln1_b = (const float*)d_in[3];
    // d_in[4..7] = wq,bq,wk,bk : dead (softmax over size-1 axis == 1 -> ctx == v)
    const float* wv    = (const float*)d_in[8];
    const float* bv    = (const float*)d_in[9];
    const float* wo    = (const float*)d_in[10];
    const float* bo    = (const float*)d_in[11];
    const float* ln2_g = (const float*)d_in[12];
    const float* ln2_b = (const float*)d_in[13];
    const float* w1    = (const float*)d_in[14];
    const float* b1    = (const float*)d_in[15];
    const float* w2    = (const float*)d_in[16];
    const float* b2    = (const float*)d_in[17];
    const float* lmbda = (const float*)d_in[18];
    const float* gat_w = (const float*)d_in[19];
    const float* gat_b = (const float*)d_in[20];
    const float* watt  = (const float*)d_in[21];
    const float* prelu = (const float*)d_in[22];
    const int* eidx    = (const int*)d_in[23];
    const int* bids    = (const int*)d_in[24];
    const int* beidx   = (const int*)d_in[25];

    const int n  = in_sizes[24];        // N entities
    const int E  = in_sizes[1];         // KG edges
    const int E2 = in_sizes[25] / 2;    // batch edges (E + N self loops)

    char* ws = (char*)d_ws;
    const size_t szND = (size_t)n * D * sizeof(float);
    size_t off = 0;
    float* bufA   = (float*)(ws + off); off += szND;                    // Z
    float* bufB   = (float*)(ws + off); off += szND;                    // gat_in
    float* dl     = (float*)(ws + off); off += (size_t)n * 4;
    float* dr     = (float*)(ws + off); off += (size_t)n * 4;
    int*   deg1   = (int*)(ws + off);   off += (size_t)n * 4;           // deg1+deg2 adjacent
    int*   deg2   = (int*)(ws + off);   off += (size_t)n * 4;           //  -> single memset
    int*   start1 = (int*)(ws + off);   off += (size_t)(n+1) * 4;
    int*   start2 = (int*)(ws + off);   off += (size_t)(n+1) * 4;
    int*   cur1   = (int*)(ws + off);   off += (size_t)n * 4;
    int*   cur2   = (int*)(ws + off);   off += (size_t)n * 4;
    int*   bsum   = (int*)(ws + off);   off += 1024 * 4;
    int*   colp1  = (int*)(ws + off);   off += (size_t)E * 4;
    float* wp1    = (float*)(ws + off); off += (size_t)E * 4;
    int*   colp2  = (int*)(ws + off);   off += (size_t)E2 * 4;
    off = (off + 15) & ~(size_t)15;
    unsigned short* Wp = (unsigned short*)(ws + off); off += (size_t)5 * 16384 * 2;

    const int nscan = (n + 255) / 256;
    const int npull = (n + 4*PW - 1) / (4*PW);

    // pack bf16 weights in B-frag order (wv, wo, w1, w2, gat_w)
    k_cvt<<<dim3(64, 5), 256, 0, stream>>>(wv, wo, w1, w2, gat_w, Wp);

    // dense block -> Z
    k_dense<<<(n + 63)/64, 256, 0, stream>>>(ent, ln1_g, ln1_b, ln2_g, ln2_b,
                                             bv, bo, b1, b2, Wp, bufA, n);

    // CSR build (both edge sets)
    hipMemsetAsync(deg1, 0, (size_t)2 * n * 4, stream);
    k_hist<<<(E + 255)/256, 256, 0, stream>>>(eidx, deg1, E);
    k_hist<<<(E2 + 255)/256, 256, 0, stream>>>(beidx, deg2, E2);

    k_scan_partial<<<nscan, 256, 0, stream>>>(deg1, bsum, n);
    k_scan_bsums<<<1, 1024, 0, stream>>>(bsum, nscan);
    k_scan_final<<<nscan, 256, 0, stream>>>(deg1, bsum, start1, cur1, n, E);
    k_fill_gcn<<<(E + 255)/256, 256, 0, stream>>>(eidx, ew, cur1, colp1, wp1, E);

    k_scan_partial<<<nscan, 256, 0, stream>>>(deg2, bsum, n);
    k_scan_bsums<<<1, 1024, 0, stream>>>(bsum, nscan);
    k_scan_final<<<nscan, 256, 0, stream>>>(deg2, bsum, start2, cur2, n, E2);
    k_fill_gat<<<(E2 + 255)/256, 256, 0, stream>>>(beidx, cur2, colp2, E2);

    // GCN pull on Z (no matvec, no atomics, no LDS)
    k_gcn_pull<<<npull, 256, 0, stream>>>(bufA, start1, colp1, wp1, lmbda,
                                          gat_b, watt, bufB, dl, dr, n);

    // GAT pull + PReLU -> out
    k_gat_out<<<npull, 256, 0, stream>>>(bufB, start2, colp2, bids, dl, dr,
                                         prelu, (float*)d_out, n);
}